// Round 8
// baseline (1510.767 us; speedup 1.0000x reference)
//
#include <hip/hip_runtime.h>
#include <math.h>

#define BB 4
#define TT 2048
#define DD 1024
#define HH 128
#define EPSF 1e-6f
#define BT (BB*TT)   // 8192
#define CC 128       // phase-2 chunk length
#define NCH (TT/CC)  // 16 chunks per batch
#define NI (TT/2)    // 1024 double-steps

typedef float f32x2 __attribute__((ext_vector_type(2)));

// ---------------------------------------------------------------------------
// Projection: P[bt][h] = sum_d x[bt][d] * W[h][d] + bias[h]
// ---------------------------------------------------------------------------
__global__ __launch_bounds__(256) void proj_kernel(
    const float* __restrict__ x,
    const float* __restrict__ Wq, const float* __restrict__ bq,
    const float* __restrict__ Wk, const float* __restrict__ bk,
    const float* __restrict__ Wv, const float* __restrict__ bv,
    float* __restrict__ Q, float* __restrict__ K, float* __restrict__ V)
{
    const int which = blockIdx.y;
    const float* W    = (which == 0) ? Wq : (which == 1) ? Wk : Wv;
    const float* bias = (which == 0) ? bq : (which == 1) ? bk : bv;
    float* P          = (which == 0) ? Q  : (which == 1) ? K  : V;

    const int row0 = blockIdx.x * 64;

    __shared__ float xT[32][68];
    __shared__ float wT[32][132];

    const int tid = threadIdx.x;
    const int tx = tid & 15;
    const int ty = tid >> 4;

    float acc[4][8];
    #pragma unroll
    for (int i = 0; i < 4; i++)
        #pragma unroll
        for (int j = 0; j < 8; j++) acc[i][j] = 0.f;

    for (int k0 = 0; k0 < DD; k0 += 32) {
        #pragma unroll
        for (int l = 0; l < 2; l++) {
            int f = tid + l * 256;
            int r = f >> 3;
            int cg = f & 7;
            float4 v = *(const float4*)(x + (size_t)(row0 + r) * DD + k0 + cg * 4);
            xT[cg*4+0][r] = v.x; xT[cg*4+1][r] = v.y;
            xT[cg*4+2][r] = v.z; xT[cg*4+3][r] = v.w;
        }
        #pragma unroll
        for (int l = 0; l < 4; l++) {
            int f = tid + l * 256;
            int h = f >> 3;
            int cg = f & 7;
            float4 v = *(const float4*)(W + (size_t)h * DD + k0 + cg * 4);
            wT[cg*4+0][h] = v.x; wT[cg*4+1][h] = v.y;
            wT[cg*4+2][h] = v.z; wT[cg*4+3][h] = v.w;
        }
        __syncthreads();
        #pragma unroll
        for (int kk = 0; kk < 32; kk++) {
            float4 xv = *(const float4*)&xT[kk][ty * 4];
            float4 w0 = *(const float4*)&wT[kk][tx * 8];
            float4 w1 = *(const float4*)&wT[kk][tx * 8 + 4];
            float xa[4] = {xv.x, xv.y, xv.z, xv.w};
            float wa[8] = {w0.x, w0.y, w0.z, w0.w, w1.x, w1.y, w1.z, w1.w};
            #pragma unroll
            for (int i = 0; i < 4; i++)
                #pragma unroll
                for (int j = 0; j < 8; j++)
                    acc[i][j] += xa[i] * wa[j];
        }
        __syncthreads();
    }

    #pragma unroll
    for (int i = 0; i < 4; i++) {
        int row = row0 + ty * 4 + i;
        #pragma unroll
        for (int j = 0; j < 8; j++) acc[i][j] += bias[tx * 8 + j];
        float4 o0 = {acc[i][0], acc[i][1], acc[i][2], acc[i][3]};
        float4 o1 = {acc[i][4], acc[i][5], acc[i][6], acc[i][7]};
        *(float4*)(P + (size_t)row * HH + tx * 8)     = o0;
        *(float4*)(P + (size_t)row * HH + tx * 8 + 4) = o1;
    }
}

// ---------------------------------------------------------------------------
// Precompute per-step scalars: rns[row] = (1/(||k||+eps), k.q).
// ---------------------------------------------------------------------------
__global__ __launch_bounds__(256) void rns_kernel(
    const float* __restrict__ K, const float* __restrict__ Q,
    float2* __restrict__ rns)
{
    const int row  = blockIdx.x * 4 + (threadIdx.x >> 6);
    const int lane = threadIdx.x & 63;
    const float* kp = K + (size_t)row * HH;
    const float* qp = Q + (size_t)row * HH;
    float k0 = kp[lane], k1 = kp[lane + 64];
    float q0 = qp[lane], q1 = qp[lane + 64];
    float p2  = k0 * k0 + k1 * k1;
    float pkq = k0 * q0 + k1 * q1;
    #pragma unroll
    for (int off = 32; off; off >>= 1) {
        p2  += __shfl_xor(p2, off);
        pkq += __shfl_xor(pkq, off);
    }
    if (lane == 0) {
        float rn = 1.0f / (sqrtf(p2) + EPSF);
        rns[row] = make_float2(rn, pkq);
    }
}

// 8-lane butterfly sum, pure DPP/VALU (no DS pipe):
// xor1 = quad_perm[1,0,3,2], xor2 = quad_perm[2,3,0,1],
// cross-quad within the 8-lane group = ROW_HALF_MIRROR (0x141).
__device__ __forceinline__ float red8(float x) {
    x += __int_as_float(__builtin_amdgcn_mov_dpp(__float_as_int(x), 0xB1,  0xF, 0xF, true));
    x += __int_as_float(__builtin_amdgcn_mov_dpp(__float_as_int(x), 0x4E,  0xF, 0xF, true));
    x += __int_as_float(__builtin_amdgcn_mov_dpp(__float_as_int(x), 0x141, 0xF, 0xF, true));
    return x;
}

// ---------------------------------------------------------------------------
// Sequential scan v9: rank-2 A-only recurrence (v8 algebra, unchanged) with
// k loaded GLOBAL->REGISTERS, prefetched one double-step ahead (ping-pong
// register arrays). v8 diagnosis: the scan is DS-pipe-instruction-bound
// (~12 cyc per ds_read_b128 wave-inst; 16/thread/double-step = ~1540 cyc/CU).
// Removing the k LDS staging halves DS instructions; only the y-broadcast
// (genuinely all-to-all) remains in LDS. The 8 VMEM loads per thread per
// double-step are issued with a full iteration (~1900 cyc) of slack.
// Padded Ybc layout: element e at (e>>4)*20 + (e&15) -> conflict-free.
// ---------------------------------------------------------------------------
#define DSTEP(I, YB, KC1, KC2, KN1, KN2)                                      \
  {                                                                           \
    f32x2 y10 = {0,0}, y11 = {0,0}, y20 = {0,0}, y21 = {0,0};                 \
    _Pragma("unroll")                                                         \
    for (int j = 0; j < 8; j++) {                                             \
        y10 += Ar0[j] * KC1[j];                                               \
        y11 += Ar1[j] * KC1[j];                                               \
        y20 += Ar0[j] * KC2[j];                                               \
        y21 += Ar1[j] * KC2[j];                                               \
    }                                                                         \
    float y1r0 = red8(y10.x + y10.y);                                         \
    float y1r1 = red8(y11.x + y11.y);                                         \
    float y2r0 = red8(y20.x + y20.y);                                         \
    float y2r1 = red8(y21.x + y21.y);                                         \
    if (o8 == 0) {                                                            \
        *(float2*)&Ybc[YB][0][woff] = make_float2(y1r0, y1r1);                \
        *(float2*)&Ybc[YB][1][woff] = make_float2(y2r0, y2r1);                \
    }                                                                         \
    if ((I) + 1 < NI) {                                                       \
        const float* kp = Kb + (size_t)(2 * ((I) + 1)) * HH + c0;             \
        _Pragma("unroll")                                                     \
        for (int j = 0; j < 4; j++) {                                         \
            float4 t1 = *(const float4*)(kp + 4 * j);                         \
            float4 t2 = *(const float4*)(kp + HH + 4 * j);                    \
            KN1[2*j] = (f32x2){t1.x, t1.y}; KN1[2*j+1] = (f32x2){t1.z, t1.w}; \
            KN2[2*j] = (f32x2){t2.x, t2.y}; KN2[2*j+1] = (f32x2){t2.z, t2.w}; \
        }                                                                     \
    }                                                                         \
    __syncthreads();                                                          \
    f32x2 av1[8], av2[8];                                                     \
    _Pragma("unroll")                                                         \
    for (int j = 0; j < 4; j++) {                                             \
        float4 t1 = *(const float4*)&Ybc[YB][0][roff + 4 * j];                \
        float4 t2 = *(const float4*)&Ybc[YB][1][roff + 4 * j];                \
        av1[2*j] = (f32x2){t1.x, t1.y}; av1[2*j+1] = (f32x2){t1.z, t1.w};     \
        av2[2*j] = (f32x2){t2.x, t2.y}; av2[2*j+1] = (f32x2){t2.z, t2.w};     \
    }                                                                         \
    f32x2 e11v = {0,0}, e21v = {0,0}, e22v = {0,0};                           \
    _Pragma("unroll")                                                         \
    for (int j = 0; j < 8; j++) {                                             \
        e11v += av1[j] * KC1[j];                                              \
        e21v += av1[j] * KC2[j];                                              \
        e22v += av2[j] * KC2[j];                                              \
    }                                                                         \
    float e11 = red8(e11v.x + e11v.y);                                        \
    float e21 = red8(e21v.x + e21v.y);                                        \
    float e22 = red8(e22v.x + e22v.y);                                        \
    const float rn1 = rs_cur.x, s1 = rs_cur.y;                                \
    const float rn2 = rs_cur.z, s2 = rs_cur.w;                                \
    const float rn1sq = rn1 * rn1;                                            \
    const float rn2sq = rn2 * rn2;                                            \
    const float i1   = __builtin_amdgcn_rcpf(1.0f + rn1sq * e11);             \
    const float beta = rn1sq * e21 * i1;                                      \
    const float i2   = __builtin_amdgcn_rcpf(1.0f + rn2sq * (e22 - beta*e21));\
    const float p2r0 = y2r0 - beta * y1r0;                                    \
    const float p2r1 = y2r1 - beta * y1r1;                                    \
    const float za1  = s1 * rn1 * i1;                                         \
    const float za2  = s2 * rn2 * i2;                                         \
    if (o8 == 0) {                                                            \
        *(float2*)(Ab + (size_t)(2 * (I))     * HH + r0) =                    \
            make_float2(za1 * y1r0, za1 * y1r1);                              \
        *(float2*)(Ab + (size_t)(2 * (I) + 1) * HH + r0) =                    \
            make_float2(za2 * p2r0, za2 * p2r1);                              \
    }                                                                         \
    const float cA1 = rn1sq * i1, cA2 = rn2sq * i2;                           \
    const f32x2 u10 = {cA1 * y1r0, cA1 * y1r0};                               \
    const f32x2 u11 = {cA1 * y1r1, cA1 * y1r1};                               \
    const f32x2 u20 = {cA2 * p2r0, cA2 * p2r0};                               \
    const f32x2 u21 = {cA2 * p2r1, cA2 * p2r1};                               \
    const f32x2 bbv = {beta, beta};                                           \
    _Pragma("unroll")                                                         \
    for (int j = 0; j < 8; j++) {                                             \
        f32x2 pp = av2[j] - bbv * av1[j];                                     \
        Ar0[j] = Ar0[j] - u10 * av1[j] - u20 * pp;                            \
        Ar1[j] = Ar1[j] - u11 * av1[j] - u21 * pp;                            \
    }                                                                         \
    rs_cur = rs_nxt;                                                          \
    if ((I) + 2 < NI) rs_nxt = ((const float4*)rns_b)[(I) + 2];               \
  }

__global__ __launch_bounds__(512, 1) void scan_kernel(
    const float* __restrict__ K, const float2* __restrict__ rns,
    float* __restrict__ Alpha)
{
    const int b   = blockIdx.x;
    const int tid = threadIdx.x;
    const int r2  = tid >> 3;      // row pair 0..63
    const int o8  = tid & 7;       // column octant
    const int c0  = o8 * 16;
    const int r0  = 2 * r2, r1 = r0 + 1;

    __shared__ float Ybc[2][2][8 * 20];   // [buf][y1/y2] broadcast, padded

    f32x2 Ar0[8], Ar1[8];
    #pragma unroll
    for (int j = 0; j < 8; j++) {
        Ar0[j].x = (c0 + 2*j     == r0) ? 1.f : 0.f;
        Ar0[j].y = (c0 + 2*j + 1 == r0) ? 1.f : 0.f;
        Ar1[j].x = (c0 + 2*j     == r1) ? 1.f : 0.f;
        Ar1[j].y = (c0 + 2*j + 1 == r1) ? 1.f : 0.f;
    }

    const float* Kb = K + (size_t)b * TT * HH;
    float*       Ab = Alpha + (size_t)b * TT * HH;
    const float2* rns_b = rns + (size_t)b * TT;

    const int woff = (r0 >> 4) * 20 + (r0 & 15);  // r0 even -> 8B aligned
    const int roff = o8 * 20;

    // k registers, ping-pong across double-steps
    f32x2 k1a[8], k2a[8], k1b[8], k2b[8];
    {
        const float* kp = Kb + c0;
        #pragma unroll
        for (int j = 0; j < 4; j++) {
            float4 t1 = *(const float4*)(kp + 4 * j);
            float4 t2 = *(const float4*)(kp + HH + 4 * j);
            k1a[2*j] = (f32x2){t1.x, t1.y}; k1a[2*j+1] = (f32x2){t1.z, t1.w};
            k2a[2*j] = (f32x2){t2.x, t2.y}; k2a[2*j+1] = (f32x2){t2.z, t2.w};
        }
    }
    float4 rs_cur = ((const float4*)rns_b)[0];
    float4 rs_nxt = ((const float4*)rns_b)[1];

    for (int i = 0; i < NI; i += 2) {
        DSTEP(i,     0, k1a, k2a, k1b, k2b)
        DSTEP(i + 1, 1, k1b, k2b, k1a, k2a)
    }
}

// ---------------------------------------------------------------------------
// Phase 2a: G[b][i] = V_chunk^T @ Alpha_chunk  (HxH), K = s over CC rows.
// ---------------------------------------------------------------------------
__global__ __launch_bounds__(256) void gram_kernel(
    const float* __restrict__ V, const float* __restrict__ Alpha,
    float* __restrict__ G)
{
    const int bi = blockIdx.x;                 // b*NCH + chunk
    const int r0 = blockIdx.y * 64;

    const float* Vc = V     + (size_t)bi * CC * HH;
    const float* Ac = Alpha + (size_t)bi * CC * HH;

    __shared__ float vT[32][68];
    __shared__ float aT[32][132];

    const int tid = threadIdx.x;
    const int tx = tid & 15, ty = tid >> 4;

    float acc[4][8];
    #pragma unroll
    for (int i = 0; i < 4; i++)
        #pragma unroll
        for (int j = 0; j < 8; j++) acc[i][j] = 0.f;

    for (int s0 = 0; s0 < CC; s0 += 32) {
        #pragma unroll
        for (int l = 0; l < 2; l++) {
            int f = tid + l * 256;
            int sr = f >> 4, rc = f & 15;
            float4 v = *(const float4*)(Vc + (size_t)(s0 + sr) * HH + r0 + rc * 4);
            *(float4*)&vT[sr][rc * 4] = v;
        }
        #pragma unroll
        for (int l = 0; l < 4; l++) {
            int f = tid + l * 256;
            int sr = f >> 5, cc = f & 31;
            float4 v = *(const float4*)(Ac + (size_t)(s0 + sr) * HH + cc * 4);
            *(float4*)&aT[sr][cc * 4] = v;
        }
        __syncthreads();
        #pragma unroll
        for (int ss = 0; ss < 32; ss++) {
            float4 vv = *(const float4*)&vT[ss][ty * 4];
            float4 a0 = *(const float4*)&aT[ss][tx * 8];
            float4 a1 = *(const float4*)&aT[ss][tx * 8 + 4];
            float va[4] = {vv.x, vv.y, vv.z, vv.w};
            float aa[8] = {a0.x, a0.y, a0.z, a0.w, a1.x, a1.y, a1.z, a1.w};
            #pragma unroll
            for (int i = 0; i < 4; i++)
                #pragma unroll
                for (int j = 0; j < 8; j++)
                    acc[i][j] += va[i] * aa[j];
        }
        __syncthreads();
    }

    #pragma unroll
    for (int i = 0; i < 4; i++) {
        float* gp = G + ((size_t)bi * HH + r0 + ty * 4 + i) * HH + tx * 8;
        float4 o0 = {acc[i][0], acc[i][1], acc[i][2], acc[i][3]};
        float4 o1 = {acc[i][4], acc[i][5], acc[i][6], acc[i][7]};
        *(float4*)gp       = o0;
        *(float4*)(gp + 4) = o1;
    }
}

// ---------------------------------------------------------------------------
// Phase 2b: exclusive prefix over chunks: Mpre[b][i] = sum_{j<i} G[b][j].
// ---------------------------------------------------------------------------
__global__ __launch_bounds__(256) void prefix_kernel(
    const float* __restrict__ G, float* __restrict__ Mpre)
{
    const int b   = blockIdx.x;
    const int idx = blockIdx.y * 256 + threadIdx.x;
    float run = 0.f;
    for (int i = 0; i < NCH; i++) {
        size_t off = ((size_t)b * NCH + i) * HH * HH + idx;
        Mpre[off] = run;
        run += G[off];
    }
}

// ---------------------------------------------------------------------------
// Phase 2c: O_half = Q_half @ Mpre^T + tril(Q_half @ Alpha^T) @ V_chunk.
// ---------------------------------------------------------------------------
__global__ __launch_bounds__(256) void ochunk_kernel(
    const float* __restrict__ Q, const float* __restrict__ Alpha,
    const float* __restrict__ V, const float* __restrict__ Mpre,
    float* __restrict__ O)
{
    const int bi = blockIdx.x;
    const int t0 = blockIdx.y * 64;            // local t base within chunk

    const float* Qc = Q     + (size_t)bi * CC * HH;
    const float* Ac = Alpha + (size_t)bi * CC * HH;
    const float* Vc = V     + (size_t)bi * CC * HH;
    const float* Mp = Mpre  + (size_t)bi * HH * HH;
    float*       Oc = O     + (size_t)bi * CC * HH;

    __shared__ float S[64][132];
    __shared__ float xT[32][68];
    __shared__ float wT[32][132];

    const int tid = threadIdx.x;
    const int tx = tid & 15, ty = tid >> 4;

    float acc[4][8];

    // ---- phase 1: S = Q_half @ Alpha^T (K = h)
    #pragma unroll
    for (int i = 0; i < 4; i++)
        #pragma unroll
        for (int j = 0; j < 8; j++) acc[i][j] = 0.f;
    for (int k0 = 0; k0 < HH; k0 += 32) {
        #pragma unroll
        for (int l = 0; l < 2; l++) {
            int f = tid + l * 256;
            int r = f >> 3, cg = f & 7;
            float4 v = *(const float4*)(Qc + (size_t)(t0 + r) * HH + k0 + cg * 4);
            xT[cg*4+0][r] = v.x; xT[cg*4+1][r] = v.y;
            xT[cg*4+2][r] = v.z; xT[cg*4+3][r] = v.w;
        }
        #pragma unroll
        for (int l = 0; l < 4; l++) {
            int f = tid + l * 256;
            int sr = f >> 3, cg = f & 7;
            float4 v = *(const float4*)(Ac + (size_t)sr * HH + k0 + cg * 4);
            wT[cg*4+0][sr] = v.x; wT[cg*4+1][sr] = v.y;
            wT[cg*4+2][sr] = v.z; wT[cg*4+3][sr] = v.w;
        }
        __syncthreads();
        #pragma unroll
        for (int kk = 0; kk < 32; kk++) {
            float4 xv = *(const float4*)&xT[kk][ty * 4];
            float4 w0 = *(const float4*)&wT[kk][tx * 8];
            float4 w1 = *(const float4*)&wT[kk][tx * 8 + 4];
            float xa[4] = {xv.x, xv.y, xv.z, xv.w};
            float wa[8] = {w0.x, w0.y, w0.z, w0.w, w1.x, w1.y, w1.z, w1.w};
            #pragma unroll
            for (int i = 0; i < 4; i++)
                #pragma unroll
                for (int j = 0; j < 8; j++)
                    acc[i][j] += xa[i] * wa[j];
        }
        __syncthreads();
    }
    #pragma unroll
    for (int i = 0; i < 4; i++) {
        int tl = t0 + ty * 4 + i;
        float m[8];
        #pragma unroll
        for (int j = 0; j < 8; j++)
            m[j] = (tx * 8 + j <= tl) ? acc[i][j] : 0.f;
        float4 o0 = {m[0], m[1], m[2], m[3]};
        float4 o1 = {m[4], m[5], m[6], m[7]};
        *(float4*)&S[ty*4+i][tx*8]     = o0;
        *(float4*)&S[ty*4+i][tx*8 + 4] = o1;
    }

    // ---- phase 2: acc = Q_half @ Mpre^T (K = h')
    #pragma unroll
    for (int i = 0; i < 4; i++)
        #pragma unroll
        for (int j = 0; j < 8; j++) acc[i][j] = 0.f;
    for (int k0 = 0; k0 < HH; k0 += 32) {
        #pragma unroll
        for (int l = 0; l < 2; l++) {
            int f = tid + l * 256;
            int r = f >> 3, cg = f & 7;
            float4 v = *(const float4*)(Qc + (size_t)(t0 + r) * HH + k0 + cg * 4);
            xT[cg*4+0][r] = v.x; xT[cg*4+1][r] = v.y;
            xT[cg*4+2][r] = v.z; xT[cg*4+3][r] = v.w;
        }
        #pragma unroll
        for (int l = 0; l < 4; l++) {
            int f = tid + l * 256;
            int h = f >> 3, cg = f & 7;
            float4 v = *(const float4*)(Mp + (size_t)h * HH + k0 + cg * 4);
            wT[cg*4+0][h] = v.x; wT[cg*4+1][h] = v.y;
            wT[cg*4+2][h] = v.z; wT[cg*4+3][h] = v.w;
        }
        __syncthreads();
        #pragma unroll
        for (int kk = 0; kk < 32; kk++) {
            float4 xv = *(const float4*)&xT[kk][ty * 4];
            float4 w0 = *(const float4*)&wT[kk][tx * 8];
            float4 w1 = *(const float4*)&wT[kk][tx * 8 + 4];
            float xa[4] = {xv.x, xv.y, xv.z, xv.w};
            float wa[8] = {w0.x, w0.y, w0.z, w0.w, w1.x, w1.y, w1.z, w1.w};
            #pragma unroll
            for (int i = 0; i < 4; i++)
                #pragma unroll
                for (int j = 0; j < 8; j++)
                    acc[i][j] += xa[i] * wa[j];
        }
        __syncthreads();
    }

    // ---- phase 3: acc += S @ V (K = s)
    for (int s0 = 0; s0 < CC; s0 += 32) {
        #pragma unroll
        for (int l = 0; l < 4; l++) {
            int f = tid + l * 256;
            int sr = f >> 5, cc = f & 31;
            float4 v = *(const float4*)(Vc + (size_t)(s0 + sr) * HH + cc * 4);
            *(float4*)&wT[sr][cc * 4] = v;
        }
        __syncthreads();
        #pragma unroll
        for (int ss = 0; ss < 32; ss++) {
            float4 w0 = *(const float4*)&wT[ss][tx * 8];
            float4 w1 = *(const float4*)&wT[ss][tx * 8 + 4];
            float wa[8] = {w0.x, w0.y, w0.z, w0.w, w1.x, w1.y, w1.z, w1.w};
            float sv[4];
            #pragma unroll
            for (int i = 0; i < 4; i++) sv[i] = S[ty*4+i][s0 + ss];
            #pragma unroll
            for (int i = 0; i < 4; i++)
                #pragma unroll
                for (int j = 0; j < 8; j++)
                    acc[i][j] += sv[i] * wa[j];
        }
        __syncthreads();
    }

    #pragma unroll
    for (int i = 0; i < 4; i++) {
        float* op = Oc + (size_t)(t0 + ty * 4 + i) * HH + tx * 8;
        float4 o0 = {acc[i][0], acc[i][1], acc[i][2], acc[i][3]};
        float4 o1 = {acc[i][4], acc[i][5], acc[i][6], acc[i][7]};
        *(float4*)op       = o0;
        *(float4*)(op + 4) = o1;
    }
}

// ---------------------------------------------------------------------------
// Output: out[bt][d] = sum_h O[bt][h] * Wo[d][h] + bo[d]
// ---------------------------------------------------------------------------
__global__ __launch_bounds__(256) void out_kernel(
    const float* __restrict__ O, const float* __restrict__ Wo,
    const float* __restrict__ bo, float* __restrict__ out)
{
    const int row0 = blockIdx.x * 64;
    const int d0   = blockIdx.y * 128;

    __shared__ float oT[32][68];
    __shared__ float woT[32][132];

    const int tid = threadIdx.x;
    const int tx = tid & 15;
    const int ty = tid >> 4;

    float acc[4][8];
    #pragma unroll
    for (int i = 0; i < 4; i++)
        #pragma unroll
        for (int j = 0; j < 8; j++) acc[i][j] = 0.f;

    for (int k0 = 0; k0 < HH; k0 += 32) {
        #pragma unroll
        for (int l = 0; l < 2; l++) {
            int f = tid + l * 256;
            int r = f >> 3;
            int cg = f & 7;
            float4 v = *(const float4*)(O + (size_t)(row0 + r) * HH + k0 + cg * 4);
            oT[cg*4+0][r] = v.x; oT[cg*4+1][r] = v.y;
            oT[cg*4+2][r] = v.z; oT[cg*4+3][r] = v.w;
        }
        #pragma unroll
        for (int l = 0; l < 4; l++) {
            int f = tid + l * 256;
            int d = f >> 3;
            int cg = f & 7;
            float4 v = *(const float4*)(Wo + (size_t)(d0 + d) * HH + k0 + cg * 4);
            woT[cg*4+0][d] = v.x; woT[cg*4+1][d] = v.y;
            woT[cg*4+2][d] = v.z; woT[cg*4+3][d] = v.w;
        }
        __syncthreads();
        #pragma unroll
        for (int kk = 0; kk < 32; kk++) {
            float4 ov = *(const float4*)&oT[kk][ty * 4];
            float4 w0 = *(const float4*)&woT[kk][tx * 8];
            float4 w1 = *(const float4*)&woT[kk][tx * 8 + 4];
            float oa[4] = {ov.x, ov.y, ov.z, ov.w};
            float wa[8] = {w0.x, w0.y, w0.z, w0.w, w1.x, w1.y, w1.z, w1.w};
            #pragma unroll
            for (int i = 0; i < 4; i++)
                #pragma unroll
                for (int j = 0; j < 8; j++)
                    acc[i][j] += oa[i] * wa[j];
        }
        __syncthreads();
    }

    #pragma unroll
    for (int i = 0; i < 4; i++) {
        int row = row0 + ty * 4 + i;
        #pragma unroll
        for (int j = 0; j < 8; j++) acc[i][j] += bo[d0 + tx * 8 + j];
        float4 o0 = {acc[i][0], acc[i][1], acc[i][2], acc[i][3]};
        float4 o1 = {acc[i][4], acc[i][5], acc[i][6], acc[i][7]};
        *(float4*)(out + (size_t)row * DD + d0 + tx * 8)     = o0;
        *(float4*)(out + (size_t)row * DD + d0 + tx * 8 + 4) = o1;
    }
}

extern "C" void kernel_launch(void* const* d_in, const int* in_sizes, int n_in,
                              void* d_out, int out_size, void* d_ws, size_t ws_size,
                              hipStream_t stream) {
    const float* x  = (const float*)d_in[0];
    const float* Wq = (const float*)d_in[1];
    const float* bq = (const float*)d_in[2];
    const float* Wk = (const float*)d_in[3];
    const float* bk = (const float*)d_in[4];
    const float* Wv = (const float*)d_in[5];
    const float* bv = (const float*)d_in[6];
    const float* Wo = (const float*)d_in[7];
    const float* bo = (const float*)d_in[8];
    float* out = (float*)d_out;

    float* ws = (float*)d_ws;
    float* Q = ws;
    float* K = ws + (size_t)BT * HH;
    float* V = ws + (size_t)2 * BT * HH;
    float* O = ws + (size_t)3 * BT * HH;

    // scratch in d_out (32 MB), all consumed before out_kernel:
    //   rns @ 0 (64 KB) | Alpha @ 1 MB (4 MB) | G @ 8 MB (4 MB) | Mpre @ 12 MB
    float*  db    = (float*)d_out;
    float2* rns   = (float2*)db;
    float*  Alpha = db + (1u << 18);
    float*  G     = db + (1u << 21);
    float*  Mpre  = db + 3u * (1u << 20);

    dim3 pgrid(BT / 64, 3);
    proj_kernel<<<pgrid, 256, 0, stream>>>(x, Wq, bq, Wk, bk, Wv, bv, Q, K, V);

    rns_kernel<<<BT / 4, 256, 0, stream>>>(K, Q, rns);

    scan_kernel<<<BB, 512, 0, stream>>>(K, rns, Alpha);

    dim3 ggrid(BB * NCH, 2);
    gram_kernel<<<ggrid, 256, 0, stream>>>(V, Alpha, G);

    dim3 fgrid(BB, HH * HH / 256);
    prefix_kernel<<<fgrid, 256, 0, stream>>>(G, Mpre);

    dim3 cgrid(BB * NCH, 2);
    ochunk_kernel<<<cgrid, 256, 0, stream>>>(Q, Alpha, V, Mpre, O);

    dim3 ogrid(BT / 64, DD / 128);
    out_kernel<<<ogrid, 256, 0, stream>>>(O, Wo, bo, out);
}

// Round 9
// 1217.581 us; speedup vs baseline: 1.2408x; 1.2408x over previous
//
#include <hip/hip_runtime.h>
#include <math.h>

#define BB 4
#define TT 2048
#define DD 1024
#define HH 128
#define EPSF 1e-6f
#define BT (BB*TT)   // 8192
#define CC 128       // phase-2 chunk length
#define NCH (TT/CC)  // 16 chunks per batch
#define NI (TT/2)    // 1024 double-steps

typedef float f32x2 __attribute__((ext_vector_type(2)));

// ---------------------------------------------------------------------------
// Projection: P[bt][h] = sum_d x[bt][d] * W[h][d] + bias[h]
// ---------------------------------------------------------------------------
__global__ __launch_bounds__(256) void proj_kernel(
    const float* __restrict__ x,
    const float* __restrict__ Wq, const float* __restrict__ bq,
    const float* __restrict__ Wk, const float* __restrict__ bk,
    const float* __restrict__ Wv, const float* __restrict__ bv,
    float* __restrict__ Q, float* __restrict__ K, float* __restrict__ V)
{
    const int which = blockIdx.y;
    const float* W    = (which == 0) ? Wq : (which == 1) ? Wk : Wv;
    const float* bias = (which == 0) ? bq : (which == 1) ? bk : bv;
    float* P          = (which == 0) ? Q  : (which == 1) ? K  : V;

    const int row0 = blockIdx.x * 64;

    __shared__ float xT[32][68];
    __shared__ float wT[32][132];

    const int tid = threadIdx.x;
    const int tx = tid & 15;
    const int ty = tid >> 4;

    float acc[4][8];
    #pragma unroll
    for (int i = 0; i < 4; i++)
        #pragma unroll
        for (int j = 0; j < 8; j++) acc[i][j] = 0.f;

    for (int k0 = 0; k0 < DD; k0 += 32) {
        #pragma unroll
        for (int l = 0; l < 2; l++) {
            int f = tid + l * 256;
            int r = f >> 3;
            int cg = f & 7;
            float4 v = *(const float4*)(x + (size_t)(row0 + r) * DD + k0 + cg * 4);
            xT[cg*4+0][r] = v.x; xT[cg*4+1][r] = v.y;
            xT[cg*4+2][r] = v.z; xT[cg*4+3][r] = v.w;
        }
        #pragma unroll
        for (int l = 0; l < 4; l++) {
            int f = tid + l * 256;
            int h = f >> 3;
            int cg = f & 7;
            float4 v = *(const float4*)(W + (size_t)h * DD + k0 + cg * 4);
            wT[cg*4+0][h] = v.x; wT[cg*4+1][h] = v.y;
            wT[cg*4+2][h] = v.z; wT[cg*4+3][h] = v.w;
        }
        __syncthreads();
        #pragma unroll
        for (int kk = 0; kk < 32; kk++) {
            float4 xv = *(const float4*)&xT[kk][ty * 4];
            float4 w0 = *(const float4*)&wT[kk][tx * 8];
            float4 w1 = *(const float4*)&wT[kk][tx * 8 + 4];
            float xa[4] = {xv.x, xv.y, xv.z, xv.w};
            float wa[8] = {w0.x, w0.y, w0.z, w0.w, w1.x, w1.y, w1.z, w1.w};
            #pragma unroll
            for (int i = 0; i < 4; i++)
                #pragma unroll
                for (int j = 0; j < 8; j++)
                    acc[i][j] += xa[i] * wa[j];
        }
        __syncthreads();
    }

    #pragma unroll
    for (int i = 0; i < 4; i++) {
        int row = row0 + ty * 4 + i;
        #pragma unroll
        for (int j = 0; j < 8; j++) acc[i][j] += bias[tx * 8 + j];
        float4 o0 = {acc[i][0], acc[i][1], acc[i][2], acc[i][3]};
        float4 o1 = {acc[i][4], acc[i][5], acc[i][6], acc[i][7]};
        *(float4*)(P + (size_t)row * HH + tx * 8)     = o0;
        *(float4*)(P + (size_t)row * HH + tx * 8 + 4) = o1;
    }
}

// ---------------------------------------------------------------------------
// Precompute per-step scalars: rns[row] = (1/(||k||+eps), k.q).
// ---------------------------------------------------------------------------
__global__ __launch_bounds__(256) void rns_kernel(
    const float* __restrict__ K, const float* __restrict__ Q,
    float2* __restrict__ rns)
{
    const int row  = blockIdx.x * 4 + (threadIdx.x >> 6);
    const int lane = threadIdx.x & 63;
    const float* kp = K + (size_t)row * HH;
    const float* qp = Q + (size_t)row * HH;
    float k0 = kp[lane], k1 = kp[lane + 64];
    float q0 = qp[lane], q1 = qp[lane + 64];
    float p2  = k0 * k0 + k1 * k1;
    float pkq = k0 * q0 + k1 * q1;
    #pragma unroll
    for (int off = 32; off; off >>= 1) {
        p2  += __shfl_xor(p2, off);
        pkq += __shfl_xor(pkq, off);
    }
    if (lane == 0) {
        float rn = 1.0f / (sqrtf(p2) + EPSF);
        rns[row] = make_float2(rn, pkq);
    }
}

// 16-lane butterfly sum, pure DPP/VALU (no DS pipe):
// quad_perm [1,0,3,2] (xor1), quad_perm [2,3,0,1] (xor2),
// ROW_HALF_MIRROR 0x141 (lane^7 == xor4 once quads uniform),
// ROW_MIRROR 0x140 (lane^15 == xor8 once 8-blocks uniform).
__device__ __forceinline__ float red16(float x) {
    x += __int_as_float(__builtin_amdgcn_mov_dpp(__float_as_int(x), 0xB1,  0xF, 0xF, true));
    x += __int_as_float(__builtin_amdgcn_mov_dpp(__float_as_int(x), 0x4E,  0xF, 0xF, true));
    x += __int_as_float(__builtin_amdgcn_mov_dpp(__float_as_int(x), 0x141, 0xF, 0xF, true));
    x += __int_as_float(__builtin_amdgcn_mov_dpp(__float_as_int(x), 0x140, 0xF, 0xF, true));
    return x;
}

// ---------------------------------------------------------------------------
// Sequential scan v10: rank-2 A-only recurrence (v8 algebra, unchanged),
// ownership reshaped to 4 rows x 8 cols per thread (16-lane row groups).
// v8 was DS-instruction-bound (16 ds_read_b128/thread/double-step); the
// reshape halves per-thread LDS reads (k refill 4, Ybc read 4) at equal
// VALU and register count -> DS wave-insts/CU 128 -> 64 per double-step.
// k stays LDS-staged (v9 showed global->reg 8x-redundant loads choke L1).
// Reductions are 16-lane pure-DPP (red16); one barrier per double-step.
// Padded layout: element e at (e>>3)*12 + (e&7) -> reads are <=2-way
// bank-aliased (free per m136).
// ---------------------------------------------------------------------------
__global__ __launch_bounds__(512, 1) void scan_kernel(
    const float* __restrict__ K, const float2* __restrict__ rns,
    float* __restrict__ Alpha)
{
    const int b   = blockIdx.x;
    const int tid = threadIdx.x;
    const int g   = tid & 15;        // column group: cols g*8 .. +8
    const int rg  = tid >> 4;        // row group: rows rg*4 .. +4
    const int c0  = g * 8;
    const int rb  = rg * 4;

    __shared__ float Ybc[2][2][16 * 12];   // [buf][y1/y2], padded
    __shared__ float kst[2][2][16 * 12];   // [buf][k1/k2], padded

    f32x2 Ar[4][4];
    #pragma unroll
    for (int i = 0; i < 4; i++)
        #pragma unroll
        for (int j = 0; j < 4; j++) {
            Ar[i][j].x = (c0 + 2*j     == rb + i) ? 1.f : 0.f;
            Ar[i][j].y = (c0 + 2*j + 1 == rb + i) ? 1.f : 0.f;
        }

    const float* Kb = K + (size_t)b * TT * HH;
    float*       Ab = Alpha + (size_t)b * TT * HH;
    const float2* rns_b = rns + (size_t)b * TT;

    const int woff = (rb >> 3) * 12 + (rb & 7);   // my rows' slot (rb%8 in {0,4})
    const int roff = g * 12;                      // my cols' read base

    // loaders: 64 threads stage the k-pair, one float4 each per double-step
    const bool ldr    = tid < 64;
    const int  whichk = tid >> 5;                 // 0=k1 1=k2
    const int  l32    = tid & 31;                 // float4 index: cols 4*l32
    const int  lpoff  = (l32 >> 1) * 12 + (l32 & 1) * 4;

    float4 pld = {0.f, 0.f, 0.f, 0.f};
    if (ldr) {
        float4 d0 = *(const float4*)(Kb + (size_t)whichk * HH + l32 * 4);
        *(float4*)&kst[0][whichk][lpoff] = d0;
        pld = *(const float4*)(Kb + (size_t)(2 + whichk) * HH + l32 * 4);
    }
    float4 rs_cur = ((const float4*)rns_b)[0];
    float4 rs_nxt = ((const float4*)rns_b)[1];
    __syncthreads();   // kst[0] ready

    f32x2 k1[4], k2[4];
    #pragma unroll
    for (int j = 0; j < 2; j++) {
        float4 t1 = *(const float4*)&kst[0][0][roff + 4 * j];
        float4 t2 = *(const float4*)&kst[0][1][roff + 4 * j];
        k1[2*j] = (f32x2){t1.x, t1.y}; k1[2*j+1] = (f32x2){t1.z, t1.w};
        k2[2*j] = (f32x2){t2.x, t2.y}; k2[2*j+1] = (f32x2){t2.z, t2.w};
    }

    for (int i = 0; i < NI; ++i) {
        const int yb = i & 1;
        const int nk = (i + 1) & 1;

        // --- y1 = A k1, y2 = A k2 for my 4 rows over my 8 cols
        float y1r[4], y2r[4];
        #pragma unroll
        for (int r = 0; r < 4; r++) {
            f32x2 a1 = {0,0}, a2 = {0,0};
            #pragma unroll
            for (int j = 0; j < 4; j++) {
                a1 += Ar[r][j] * k1[j];
                a2 += Ar[r][j] * k2[j];
            }
            y1r[r] = red16(a1.x + a1.y);
            y2r[r] = red16(a2.x + a2.y);
        }
        if (g == 0) {
            float4 w1 = {y1r[0], y1r[1], y1r[2], y1r[3]};
            float4 w2 = {y2r[0], y2r[1], y2r[2], y2r[3]};
            *(float4*)&Ybc[yb][0][woff] = w1;
            *(float4*)&Ybc[yb][1][woff] = w2;
        }

        // stage k-pair for iter i+1; prefetch pair for i+2
        if (ldr && i + 1 < NI) {
            *(float4*)&kst[nk][whichk][lpoff] = pld;
            if (i + 2 < NI)
                pld = *(const float4*)(Kb + (size_t)(2*(i+2) + whichk) * HH + l32 * 4);
        }

        __syncthreads();   // Ybc[yb] + kst[nk] ready

        // --- read y1,y2 vectors at my 8 cols
        f32x2 av1[4], av2[4];
        #pragma unroll
        for (int j = 0; j < 2; j++) {
            float4 t1 = *(const float4*)&Ybc[yb][0][roff + 4 * j];
            float4 t2 = *(const float4*)&Ybc[yb][1][roff + 4 * j];
            av1[2*j] = (f32x2){t1.x, t1.y}; av1[2*j+1] = (f32x2){t1.z, t1.w};
            av2[2*j] = (f32x2){t2.x, t2.y}; av2[2*j+1] = (f32x2){t2.z, t2.w};
        }

        // --- e11 = k1.y1, e21 = k2.y1, e22 = k2.y2
        f32x2 e11v = {0,0}, e21v = {0,0}, e22v = {0,0};
        #pragma unroll
        for (int j = 0; j < 4; j++) {
            e11v += av1[j] * k1[j];
            e21v += av1[j] * k2[j];
            e22v += av2[j] * k2[j];
        }
        float e11 = red16(e11v.x + e11v.y);
        float e21 = red16(e21v.x + e21v.y);
        float e22 = red16(e22v.x + e22v.y);

        // refill k1,k2 for iter i+1 (register values for THIS iter already
        // consumed by the e-dots above)
        #pragma unroll
        for (int j = 0; j < 2; j++) {
            float4 t1 = *(const float4*)&kst[nk][0][roff + 4 * j];
            float4 t2 = *(const float4*)&kst[nk][1][roff + 4 * j];
            k1[2*j] = (f32x2){t1.x, t1.y}; k1[2*j+1] = (f32x2){t1.z, t1.w};
            k2[2*j] = (f32x2){t2.x, t2.y}; k2[2*j+1] = (f32x2){t2.z, t2.w};
        }

        // --- scalars (exact rank-2 recurrence, v8-verified)
        const float rn1 = rs_cur.x, s1 = rs_cur.y;
        const float rn2 = rs_cur.z, s2 = rs_cur.w;
        const float rn1sq = rn1 * rn1;
        const float rn2sq = rn2 * rn2;
        const float i1   = __builtin_amdgcn_rcpf(1.0f + rn1sq * e11);
        const float beta = rn1sq * e21 * i1;
        const float i2   = __builtin_amdgcn_rcpf(1.0f + rn2sq * (e22 - beta * e21));
        const float za1  = s1 * rn1 * i1;
        const float za2  = s2 * rn2 * i2;
        float p2r[4];
        #pragma unroll
        for (int r = 0; r < 4; r++) p2r[r] = y2r[r] - beta * y1r[r];

        if (g == 0) {
            float4 a1w = {za1*y1r[0], za1*y1r[1], za1*y1r[2], za1*y1r[3]};
            float4 a2w = {za2*p2r[0], za2*p2r[1], za2*p2r[2], za2*p2r[3]};
            *(float4*)(Ab + (size_t)(2*i)     * HH + rb) = a1w;
            *(float4*)(Ab + (size_t)(2*i + 1) * HH + rb) = a2w;
        }

        // --- rank-2 update of A
        const float cA1 = rn1sq * i1, cA2 = rn2sq * i2;
        const f32x2 bbv = {beta, beta};
        f32x2 pp[4];
        #pragma unroll
        for (int j = 0; j < 4; j++) pp[j] = av2[j] - bbv * av1[j];
        #pragma unroll
        for (int r = 0; r < 4; r++) {
            const f32x2 u1 = {cA1 * y1r[r], cA1 * y1r[r]};
            const f32x2 u2 = {cA2 * p2r[r], cA2 * p2r[r]};
            #pragma unroll
            for (int j = 0; j < 4; j++)
                Ar[r][j] = Ar[r][j] - u1 * av1[j] - u2 * pp[j];
        }

        rs_cur = rs_nxt;
        if (i + 2 < NI) rs_nxt = ((const float4*)rns_b)[i + 2];
    }
}

// ---------------------------------------------------------------------------
// Phase 2a: G[b][i] = V_chunk^T @ Alpha_chunk  (HxH), K = s over CC rows.
// ---------------------------------------------------------------------------
__global__ __launch_bounds__(256) void gram_kernel(
    const float* __restrict__ V, const float* __restrict__ Alpha,
    float* __restrict__ G)
{
    const int bi = blockIdx.x;                 // b*NCH + chunk
    const int r0 = blockIdx.y * 64;

    const float* Vc = V     + (size_t)bi * CC * HH;
    const float* Ac = Alpha + (size_t)bi * CC * HH;

    __shared__ float vT[32][68];
    __shared__ float aT[32][132];

    const int tid = threadIdx.x;
    const int tx = tid & 15, ty = tid >> 4;

    float acc[4][8];
    #pragma unroll
    for (int i = 0; i < 4; i++)
        #pragma unroll
        for (int j = 0; j < 8; j++) acc[i][j] = 0.f;

    for (int s0 = 0; s0 < CC; s0 += 32) {
        #pragma unroll
        for (int l = 0; l < 2; l++) {
            int f = tid + l * 256;
            int sr = f >> 4, rc = f & 15;
            float4 v = *(const float4*)(Vc + (size_t)(s0 + sr) * HH + r0 + rc * 4);
            *(float4*)&vT[sr][rc * 4] = v;
        }
        #pragma unroll
        for (int l = 0; l < 4; l++) {
            int f = tid + l * 256;
            int sr = f >> 5, cc = f & 31;
            float4 v = *(const float4*)(Ac + (size_t)(s0 + sr) * HH + cc * 4);
            *(float4*)&aT[sr][cc * 4] = v;
        }
        __syncthreads();
        #pragma unroll
        for (int ss = 0; ss < 32; ss++) {
            float4 vv = *(const float4*)&vT[ss][ty * 4];
            float4 a0 = *(const float4*)&aT[ss][tx * 8];
            float4 a1 = *(const float4*)&aT[ss][tx * 8 + 4];
            float va[4] = {vv.x, vv.y, vv.z, vv.w};
            float aa[8] = {a0.x, a0.y, a0.z, a0.w, a1.x, a1.y, a1.z, a1.w};
            #pragma unroll
            for (int i = 0; i < 4; i++)
                #pragma unroll
                for (int j = 0; j < 8; j++)
                    acc[i][j] += va[i] * aa[j];
        }
        __syncthreads();
    }

    #pragma unroll
    for (int i = 0; i < 4; i++) {
        float* gp = G + ((size_t)bi * HH + r0 + ty * 4 + i) * HH + tx * 8;
        float4 o0 = {acc[i][0], acc[i][1], acc[i][2], acc[i][3]};
        float4 o1 = {acc[i][4], acc[i][5], acc[i][6], acc[i][7]};
        *(float4*)gp       = o0;
        *(float4*)(gp + 4) = o1;
    }
}

// ---------------------------------------------------------------------------
// Phase 2b: exclusive prefix over chunks: Mpre[b][i] = sum_{j<i} G[b][j].
// ---------------------------------------------------------------------------
__global__ __launch_bounds__(256) void prefix_kernel(
    const float* __restrict__ G, float* __restrict__ Mpre)
{
    const int b   = blockIdx.x;
    const int idx = blockIdx.y * 256 + threadIdx.x;
    float run = 0.f;
    for (int i = 0; i < NCH; i++) {
        size_t off = ((size_t)b * NCH + i) * HH * HH + idx;
        Mpre[off] = run;
        run += G[off];
    }
}

// ---------------------------------------------------------------------------
// Phase 2c: O_half = Q_half @ Mpre^T + tril(Q_half @ Alpha^T) @ V_chunk.
// ---------------------------------------------------------------------------
__global__ __launch_bounds__(256) void ochunk_kernel(
    const float* __restrict__ Q, const float* __restrict__ Alpha,
    const float* __restrict__ V, const float* __restrict__ Mpre,
    float* __restrict__ O)
{
    const int bi = blockIdx.x;
    const int t0 = blockIdx.y * 64;            // local t base within chunk

    const float* Qc = Q     + (size_t)bi * CC * HH;
    const float* Ac = Alpha + (size_t)bi * CC * HH;
    const float* Vc = V     + (size_t)bi * CC * HH;
    const float* Mp = Mpre  + (size_t)bi * HH * HH;
    float*       Oc = O     + (size_t)bi * CC * HH;

    __shared__ float S[64][132];
    __shared__ float xT[32][68];
    __shared__ float wT[32][132];

    const int tid = threadIdx.x;
    const int tx = tid & 15, ty = tid >> 4;

    float acc[4][8];

    // ---- phase 1: S = Q_half @ Alpha^T (K = h)
    #pragma unroll
    for (int i = 0; i < 4; i++)
        #pragma unroll
        for (int j = 0; j < 8; j++) acc[i][j] = 0.f;
    for (int k0 = 0; k0 < HH; k0 += 32) {
        #pragma unroll
        for (int l = 0; l < 2; l++) {
            int f = tid + l * 256;
            int r = f >> 3, cg = f & 7;
            float4 v = *(const float4*)(Qc + (size_t)(t0 + r) * HH + k0 + cg * 4);
            xT[cg*4+0][r] = v.x; xT[cg*4+1][r] = v.y;
            xT[cg*4+2][r] = v.z; xT[cg*4+3][r] = v.w;
        }
        #pragma unroll
        for (int l = 0; l < 4; l++) {
            int f = tid + l * 256;
            int sr = f >> 3, cg = f & 7;
            float4 v = *(const float4*)(Ac + (size_t)sr * HH + k0 + cg * 4);
            wT[cg*4+0][sr] = v.x; wT[cg*4+1][sr] = v.y;
            wT[cg*4+2][sr] = v.z; wT[cg*4+3][sr] = v.w;
        }
        __syncthreads();
        #pragma unroll
        for (int kk = 0; kk < 32; kk++) {
            float4 xv = *(const float4*)&xT[kk][ty * 4];
            float4 w0 = *(const float4*)&wT[kk][tx * 8];
            float4 w1 = *(const float4*)&wT[kk][tx * 8 + 4];
            float xa[4] = {xv.x, xv.y, xv.z, xv.w};
            float wa[8] = {w0.x, w0.y, w0.z, w0.w, w1.x, w1.y, w1.z, w1.w};
            #pragma unroll
            for (int i = 0; i < 4; i++)
                #pragma unroll
                for (int j = 0; j < 8; j++)
                    acc[i][j] += xa[i] * wa[j];
        }
        __syncthreads();
    }
    #pragma unroll
    for (int i = 0; i < 4; i++) {
        int tl = t0 + ty * 4 + i;
        float m[8];
        #pragma unroll
        for (int j = 0; j < 8; j++)
            m[j] = (tx * 8 + j <= tl) ? acc[i][j] : 0.f;
        float4 o0 = {m[0], m[1], m[2], m[3]};
        float4 o1 = {m[4], m[5], m[6], m[7]};
        *(float4*)&S[ty*4+i][tx*8]     = o0;
        *(float4*)&S[ty*4+i][tx*8 + 4] = o1;
    }

    // ---- phase 2: acc = Q_half @ Mpre^T (K = h')
    #pragma unroll
    for (int i = 0; i < 4; i++)
        #pragma unroll
        for (int j = 0; j < 8; j++) acc[i][j] = 0.f;
    for (int k0 = 0; k0 < HH; k0 += 32) {
        #pragma unroll
        for (int l = 0; l < 2; l++) {
            int f = tid + l * 256;
            int r = f >> 3, cg = f & 7;
            float4 v = *(const float4*)(Qc + (size_t)(t0 + r) * HH + k0 + cg * 4);
            xT[cg*4+0][r] = v.x; xT[cg*4+1][r] = v.y;
            xT[cg*4+2][r] = v.z; xT[cg*4+3][r] = v.w;
        }
        #pragma unroll
        for (int l = 0; l < 4; l++) {
            int f = tid + l * 256;
            int h = f >> 3, cg = f & 7;
            float4 v = *(const float4*)(Mp + (size_t)h * HH + k0 + cg * 4);
            wT[cg*4+0][h] = v.x; wT[cg*4+1][h] = v.y;
            wT[cg*4+2][h] = v.z; wT[cg*4+3][h] = v.w;
        }
        __syncthreads();
        #pragma unroll
        for (int kk = 0; kk < 32; kk++) {
            float4 xv = *(const float4*)&xT[kk][ty * 4];
            float4 w0 = *(const float4*)&wT[kk][tx * 8];
            float4 w1 = *(const float4*)&wT[kk][tx * 8 + 4];
            float xa[4] = {xv.x, xv.y, xv.z, xv.w};
            float wa[8] = {w0.x, w0.y, w0.z, w0.w, w1.x, w1.y, w1.z, w1.w};
            #pragma unroll
            for (int i = 0; i < 4; i++)
                #pragma unroll
                for (int j = 0; j < 8; j++)
                    acc[i][j] += xa[i] * wa[j];
        }
        __syncthreads();
    }

    // ---- phase 3: acc += S @ V (K = s)
    for (int s0 = 0; s0 < CC; s0 += 32) {
        #pragma unroll
        for (int l = 0; l < 4; l++) {
            int f = tid + l * 256;
            int sr = f >> 5, cc = f & 31;
            float4 v = *(const float4*)(Vc + (size_t)(s0 + sr) * HH + cc * 4);
            *(float4*)&wT[sr][cc * 4] = v;
        }
        __syncthreads();
        #pragma unroll
        for (int ss = 0; ss < 32; ss++) {
            float4 w0 = *(const float4*)&wT[ss][tx * 8];
            float4 w1 = *(const float4*)&wT[ss][tx * 8 + 4];
            float wa[8] = {w0.x, w0.y, w0.z, w0.w, w1.x, w1.y, w1.z, w1.w};
            float sv[4];
            #pragma unroll
            for (int i = 0; i < 4; i++) sv[i] = S[ty*4+i][s0 + ss];
            #pragma unroll
            for (int i = 0; i < 4; i++)
                #pragma unroll
                for (int j = 0; j < 8; j++)
                    acc[i][j] += sv[i] * wa[j];
        }
        __syncthreads();
    }

    #pragma unroll
    for (int i = 0; i < 4; i++) {
        float* op = Oc + (size_t)(t0 + ty * 4 + i) * HH + tx * 8;
        float4 o0 = {acc[i][0], acc[i][1], acc[i][2], acc[i][3]};
        float4 o1 = {acc[i][4], acc[i][5], acc[i][6], acc[i][7]};
        *(float4*)op       = o0;
        *(float4*)(op + 4) = o1;
    }
}

// ---------------------------------------------------------------------------
// Output: out[bt][d] = sum_h O[bt][h] * Wo[d][h] + bo[d]
// ---------------------------------------------------------------------------
__global__ __launch_bounds__(256) void out_kernel(
    const float* __restrict__ O, const float* __restrict__ Wo,
    const float* __restrict__ bo, float* __restrict__ out)
{
    const int row0 = blockIdx.x * 64;
    const int d0   = blockIdx.y * 128;

    __shared__ float oT[32][68];
    __shared__ float woT[32][132];

    const int tid = threadIdx.x;
    const int tx = tid & 15;
    const int ty = tid >> 4;

    float acc[4][8];
    #pragma unroll
    for (int i = 0; i < 4; i++)
        #pragma unroll
        for (int j = 0; j < 8; j++) acc[i][j] = 0.f;

    for (int k0 = 0; k0 < HH; k0 += 32) {
        #pragma unroll
        for (int l = 0; l < 2; l++) {
            int f = tid + l * 256;
            int r = f >> 3;
            int cg = f & 7;
            float4 v = *(const float4*)(O + (size_t)(row0 + r) * HH + k0 + cg * 4);
            oT[cg*4+0][r] = v.x; oT[cg*4+1][r] = v.y;
            oT[cg*4+2][r] = v.z; oT[cg*4+3][r] = v.w;
        }
        #pragma unroll
        for (int l = 0; l < 4; l++) {
            int f = tid + l * 256;
            int d = f >> 3;
            int cg = f & 7;
            float4 v = *(const float4*)(Wo + (size_t)(d0 + d) * HH + k0 + cg * 4);
            woT[cg*4+0][d] = v.x; woT[cg*4+1][d] = v.y;
            woT[cg*4+2][d] = v.z; woT[cg*4+3][d] = v.w;
        }
        __syncthreads();
        #pragma unroll
        for (int kk = 0; kk < 32; kk++) {
            float4 ov = *(const float4*)&oT[kk][ty * 4];
            float4 w0 = *(const float4*)&woT[kk][tx * 8];
            float4 w1 = *(const float4*)&woT[kk][tx * 8 + 4];
            float oa[4] = {ov.x, ov.y, ov.z, ov.w};
            float wa[8] = {w0.x, w0.y, w0.z, w0.w, w1.x, w1.y, w1.z, w1.w};
            #pragma unroll
            for (int i = 0; i < 4; i++)
                #pragma unroll
                for (int j = 0; j < 8; j++)
                    acc[i][j] += oa[i] * wa[j];
        }
        __syncthreads();
    }

    #pragma unroll
    for (int i = 0; i < 4; i++) {
        int row = row0 + ty * 4 + i;
        #pragma unroll
        for (int j = 0; j < 8; j++) acc[i][j] += bo[d0 + tx * 8 + j];
        float4 o0 = {acc[i][0], acc[i][1], acc[i][2], acc[i][3]};
        float4 o1 = {acc[i][4], acc[i][5], acc[i][6], acc[i][7]};
        *(float4*)(out + (size_t)row * DD + d0 + tx * 8)     = o0;
        *(float4*)(out + (size_t)row * DD + d0 + tx * 8 + 4) = o1;
    }
}

extern "C" void kernel_launch(void* const* d_in, const int* in_sizes, int n_in,
                              void* d_out, int out_size, void* d_ws, size_t ws_size,
                              hipStream_t stream) {
    const float* x  = (const float*)d_in[0];
    const float* Wq = (const float*)d_in[1];
    const float* bq = (const float*)d_in[2];
    const float* Wk = (const float*)d_in[3];
    const float* bk = (const float*)d_in[4];
    const float* Wv = (const float*)d_in[5];
    const float* bv = (const float*)d_in[6];
    const float* Wo = (const float*)d_in[7];
    const float* bo = (const float*)d_in[8];
    float* out = (float*)d_out;

    float* ws = (float*)d_ws;
    float* Q = ws;
    float* K = ws + (size_t)BT * HH;
    float* V = ws + (size_t)2 * BT * HH;
    float* O = ws + (size_t)3 * BT * HH;

    // scratch in d_out (32 MB), all consumed before out_kernel:
    //   rns @ 0 (64 KB) | Alpha @ 1 MB (4 MB) | G @ 8 MB (4 MB) | Mpre @ 12 MB
    float*  db    = (float*)d_out;
    float2* rns   = (float2*)db;
    float*  Alpha = db + (1u << 18);
    float*  G     = db + (1u << 21);
    float*  Mpre  = db + 3u * (1u << 20);

    dim3 pgrid(BT / 64, 3);
    proj_kernel<<<pgrid, 256, 0, stream>>>(x, Wq, bq, Wk, bk, Wv, bv, Q, K, V);

    rns_kernel<<<BT / 4, 256, 0, stream>>>(K, Q, rns);

    scan_kernel<<<BB, 512, 0, stream>>>(K, rns, Alpha);

    dim3 ggrid(BB * NCH, 2);
    gram_kernel<<<ggrid, 256, 0, stream>>>(V, Alpha, G);

    dim3 fgrid(BB, HH * HH / 256);
    prefix_kernel<<<fgrid, 256, 0, stream>>>(G, Mpre);

    dim3 cgrid(BB * NCH, 2);
    ochunk_kernel<<<cgrid, 256, 0, stream>>>(Q, Alpha, V, Mpre, O);

    dim3 ogrid(BT / 64, DD / 128);
    out_kernel<<<ogrid, 256, 0, stream>>>(O, Wo, bo, out);
}

// Round 11
// 1071.443 us; speedup vs baseline: 1.4100x; 1.1364x over previous
//
#include <hip/hip_runtime.h>
#include <math.h>

#define BB 4
#define TT 2048
#define DD 1024
#define HH 128
#define EPSF 1e-6f
#define BT (BB*TT)   // 8192
#define CC 128       // phase-2 chunk length
#define NCH (TT/CC)  // 16 chunks per batch
#define NI (TT/2)    // 1024 double-steps

typedef float f32x2 __attribute__((ext_vector_type(2)));

// 8-lane butterfly sum, pure DPP/VALU (no DS pipe)
__device__ __forceinline__ float red8(float x) {
    x += __int_as_float(__builtin_amdgcn_mov_dpp(__float_as_int(x), 0xB1,  0xF, 0xF, true));
    x += __int_as_float(__builtin_amdgcn_mov_dpp(__float_as_int(x), 0x4E,  0xF, 0xF, true));
    x += __int_as_float(__builtin_amdgcn_mov_dpp(__float_as_int(x), 0x141, 0xF, 0xF, true));
    return x;
}
// 16-lane butterfly sum (adds ROW_MIRROR)
__device__ __forceinline__ float red16(float x) {
    x = red8(x);
    x += __int_as_float(__builtin_amdgcn_mov_dpp(__float_as_int(x), 0x140, 0xF, 0xF, true));
    return x;
}

// ---------------------------------------------------------------------------
// 512-thread projection tile: P[row0..row0+64][0..128) = x @ W^T + bias.
// mode 0: plain; mode 1: epilogue computes rn[row] = 1/(||k||+eps) (P is K);
// mode 2: epilogue computes aux[row] = s = (P-row . Kmat-row) (P is Q).
// Row group = 16 consecutive lanes (tx) -> red16 DPP reductions.
// ---------------------------------------------------------------------------
__device__ __forceinline__ void proj512(
    const float* __restrict__ x, const float* __restrict__ W,
    const float* __restrict__ bias, float* __restrict__ P,
    int row0, int mode, float* __restrict__ aux,
    const float* __restrict__ Kmat)
{
    __shared__ float xT[32][68];
    __shared__ float wT[32][132];

    const int tid = threadIdx.x;
    const int tx = tid & 15;
    const int ty = tid >> 4;       // 0..31, rows ty*2 .. +2

    float acc[2][8];
    #pragma unroll
    for (int i = 0; i < 2; i++)
        #pragma unroll
        for (int j = 0; j < 8; j++) acc[i][j] = 0.f;

    for (int k0 = 0; k0 < DD; k0 += 32) {
        {   // xT: 64 rows x 32 k = 512 float4, one per thread
            int r = tid >> 3, cg = tid & 7;
            float4 v = *(const float4*)(x + (size_t)(row0 + r) * DD + k0 + cg * 4);
            xT[cg*4+0][r] = v.x; xT[cg*4+1][r] = v.y;
            xT[cg*4+2][r] = v.z; xT[cg*4+3][r] = v.w;
        }
        #pragma unroll
        for (int l = 0; l < 2; l++) {   // wT: 128 h x 32 k = 1024 float4
            int f = tid + l * 512;
            int h = f >> 3, cg = f & 7;
            float4 v = *(const float4*)(W + (size_t)h * DD + k0 + cg * 4);
            wT[cg*4+0][h] = v.x; wT[cg*4+1][h] = v.y;
            wT[cg*4+2][h] = v.z; wT[cg*4+3][h] = v.w;
        }
        __syncthreads();
        #pragma unroll
        for (int kk = 0; kk < 32; kk++) {
            float2 xv = *(const float2*)&xT[kk][ty * 2];
            float4 w0 = *(const float4*)&wT[kk][tx * 8];
            float4 w1 = *(const float4*)&wT[kk][tx * 8 + 4];
            float xa[2] = {xv.x, xv.y};
            float wa[8] = {w0.x, w0.y, w0.z, w0.w, w1.x, w1.y, w1.z, w1.w};
            #pragma unroll
            for (int i = 0; i < 2; i++)
                #pragma unroll
                for (int j = 0; j < 8; j++)
                    acc[i][j] += xa[i] * wa[j];
        }
        __syncthreads();
    }

    #pragma unroll
    for (int i = 0; i < 2; i++) {
        int row = row0 + ty * 2 + i;
        #pragma unroll
        for (int j = 0; j < 8; j++) acc[i][j] += bias[tx * 8 + j];
        float4 o0 = {acc[i][0], acc[i][1], acc[i][2], acc[i][3]};
        float4 o1 = {acc[i][4], acc[i][5], acc[i][6], acc[i][7]};
        *(float4*)(P + (size_t)row * HH + tx * 8)     = o0;
        *(float4*)(P + (size_t)row * HH + tx * 8 + 4) = o1;
    }

    if (mode == 1) {                 // rn = 1/(||k|| + eps)
        #pragma unroll
        for (int i = 0; i < 2; i++) {
            float p = 0.f;
            #pragma unroll
            for (int j = 0; j < 8; j++) p += acc[i][j] * acc[i][j];
            p = red16(p);
            if (tx == 0) aux[row0 + ty * 2 + i] = 1.0f / (sqrtf(p) + EPSF);
        }
    } else if (mode == 2) {          // s = q . k
        #pragma unroll
        for (int i = 0; i < 2; i++) {
            int row = row0 + ty * 2 + i;
            float4 ka = *(const float4*)(Kmat + (size_t)row * HH + tx * 8);
            float4 kb = *(const float4*)(Kmat + (size_t)row * HH + tx * 8 + 4);
            float p = acc[i][0]*ka.x + acc[i][1]*ka.y + acc[i][2]*ka.z + acc[i][3]*ka.w
                    + acc[i][4]*kb.x + acc[i][5]*kb.y + acc[i][6]*kb.z + acc[i][7]*kb.w;
            p = red16(p);
            if (tx == 0) aux[row] = p;
        }
    }
}

// K projection + rn epilogue (must precede the fused kernel).
__global__ __launch_bounds__(512) void projk_kernel(
    const float* __restrict__ x, const float* __restrict__ Wk,
    const float* __restrict__ bk, float* __restrict__ K,
    float* __restrict__ rn)
{
    proj512(x, Wk, bk, K, blockIdx.x * 64, 1, rn, nullptr);
}

// ---------------------------------------------------------------------------
// Fused kernel: blocks 0..3 run the v8 scan (UNCHANGED structure, 832us
// verified); blocks 4..255 project Q (+s epilogue) and V on otherwise-idle
// CUs. Zero data dependency between the paths; 256 blocks co-resident.
// Scan consumes only K + rn and emits UNSCALED z (alpha = s*z folded into
// phase-2 staging).
// BUGFIX vs R10: kst loader slot formula restored to v8's 8x20 mapping
//   lpoff = (l32>>2)*20 + (l32&3)*4   (element e at (e>>4)*20 + (e&15)).
// R10 had v10's 16x12 formula -> scattered k -> absmax 678.
// ---------------------------------------------------------------------------
__global__ __launch_bounds__(512, 1) void fused_kernel(
    const float* __restrict__ x,
    const float* __restrict__ Wq, const float* __restrict__ bq,
    const float* __restrict__ Wv, const float* __restrict__ bv,
    const float* __restrict__ K, const float* __restrict__ rn,
    float* __restrict__ Q, float* __restrict__ V,
    float* __restrict__ Sarr, float* __restrict__ Z)
{
    __shared__ float Ybc[2][2][8 * 20];   // scan: [buf][y1/y2], padded
    __shared__ float kst[2][2][8 * 20];   // scan: [buf][k1/k2], padded

    if (blockIdx.x >= BB) {
        // ---- worker path: Q and V projections (grid-stride over 256 tiles)
        const int wb = blockIdx.x - BB;          // 0..251
        for (int t = wb; t < 256; t += 252) {
            const int which = t >> 7;            // 0 = Q, 1 = V
            const int tile  = t & 127;
            if (which == 0)
                proj512(x, Wq, bq, Q, tile * 64, 2, Sarr, K);
            else
                proj512(x, Wv, bv, V, tile * 64, 0, nullptr, nullptr);
        }
        return;
    }

    // ---- scan path (v8, rank-2 A-only recurrence; rn-only scalars)
    const int b   = blockIdx.x;
    const int tid = threadIdx.x;
    const int r2  = tid >> 3;      // row pair 0..63
    const int o8  = tid & 7;       // column octant
    const int c0  = o8 * 16;
    const int r0  = 2 * r2, r1 = r0 + 1;

    f32x2 Ar0[8], Ar1[8];
    #pragma unroll
    for (int j = 0; j < 8; j++) {
        Ar0[j].x = (c0 + 2*j     == r0) ? 1.f : 0.f;
        Ar0[j].y = (c0 + 2*j + 1 == r0) ? 1.f : 0.f;
        Ar1[j].x = (c0 + 2*j     == r1) ? 1.f : 0.f;
        Ar1[j].y = (c0 + 2*j + 1 == r1) ? 1.f : 0.f;
    }

    const float* Kb = K + (size_t)b * TT * HH;
    float*       Zb = Z + (size_t)b * TT * HH;
    const float* rn_b = rn + (size_t)b * TT;

    const int woff = (r0 >> 4) * 20 + (r0 & 15);  // r0 even -> 8B aligned
    const int roff = o8 * 20;

    const bool ldr    = tid < 64;
    const int  whichk = tid >> 5;                 // 0=k1 1=k2
    const int  l32    = tid & 31;
    const int  lpoff  = (l32 >> 2) * 20 + (l32 & 3) * 4;   // v8 8x20 mapping

    float4 pld = {0.f, 0.f, 0.f, 0.f};
    if (ldr) {
        float4 d0 = *(const float4*)(Kb + (size_t)whichk * HH + l32 * 4);
        *(float4*)&kst[0][whichk][lpoff] = d0;
        pld = *(const float4*)(Kb + (size_t)(2 + whichk) * HH + l32 * 4);
    }
    float2 rs_cur = ((const float2*)rn_b)[0];
    float2 rs_nxt = ((const float2*)rn_b)[1];
    __syncthreads();   // kst[0] ready

    f32x2 k1[8], k2[8];
    #pragma unroll
    for (int j = 0; j < 4; j++) {
        float4 t1 = *(const float4*)&kst[0][0][roff + 4 * j];
        float4 t2 = *(const float4*)&kst[0][1][roff + 4 * j];
        k1[2*j] = (f32x2){t1.x, t1.y}; k1[2*j+1] = (f32x2){t1.z, t1.w};
        k2[2*j] = (f32x2){t2.x, t2.y}; k2[2*j+1] = (f32x2){t2.z, t2.w};
    }

    for (int i = 0; i < NI; ++i) {
        const int yb = i & 1;
        const int nk = (i + 1) & 1;

        // --- y1 = A k1, y2 = A k2 partials for my 2 rows over my 16 cols
        f32x2 y10 = {0,0}, y11 = {0,0}, y20 = {0,0}, y21 = {0,0};
        #pragma unroll
        for (int j = 0; j < 8; j++) {
            y10 += Ar0[j] * k1[j];
            y11 += Ar1[j] * k1[j];
            y20 += Ar0[j] * k2[j];
            y21 += Ar1[j] * k2[j];
        }
        float y1r0 = red8(y10.x + y10.y);
        float y1r1 = red8(y11.x + y11.y);
        float y2r0 = red8(y20.x + y20.y);
        float y2r1 = red8(y21.x + y21.y);
        if (o8 == 0) {
            *(float2*)&Ybc[yb][0][woff] = make_float2(y1r0, y1r1);
            *(float2*)&Ybc[yb][1][woff] = make_float2(y2r0, y2r1);
        }

        // stage k-pair for iter i+1; prefetch pair for i+2
        if (ldr && i + 1 < NI) {
            *(float4*)&kst[nk][whichk][lpoff] = pld;
            if (i + 2 < NI)
                pld = *(const float4*)(Kb + (size_t)(2*(i+2) + whichk) * HH + l32 * 4);
        }

        __syncthreads();   // Ybc[yb] + kst[nk] ready

        // --- read y1,y2 vectors at my 16 cols
        f32x2 av1[8], av2[8];
        #pragma unroll
        for (int j = 0; j < 4; j++) {
            float4 t1 = *(const float4*)&Ybc[yb][0][roff + 4 * j];
            float4 t2 = *(const float4*)&Ybc[yb][1][roff + 4 * j];
            av1[2*j] = (f32x2){t1.x, t1.y}; av1[2*j+1] = (f32x2){t1.z, t1.w};
            av2[2*j] = (f32x2){t2.x, t2.y}; av2[2*j+1] = (f32x2){t2.z, t2.w};
        }

        // --- e11 = k1.y1, e21 = k2.y1, e22 = k2.y2
        f32x2 e11v = {0,0}, e21v = {0,0}, e22v = {0,0};
        #pragma unroll
        for (int j = 0; j < 8; j++) {
            e11v += av1[j] * k1[j];
            e21v += av1[j] * k2[j];
            e22v += av2[j] * k2[j];
        }
        float e11 = red8(e11v.x + e11v.y);
        float e21 = red8(e21v.x + e21v.y);
        float e22 = red8(e22v.x + e22v.y);

        // refill k1,k2 for iter i+1
        #pragma unroll
        for (int j = 0; j < 4; j++) {
            float4 t1 = *(const float4*)&kst[nk][0][roff + 4 * j];
            float4 t2 = *(const float4*)&kst[nk][1][roff + 4 * j];
            k1[2*j] = (f32x2){t1.x, t1.y}; k1[2*j+1] = (f32x2){t1.z, t1.w};
            k2[2*j] = (f32x2){t2.x, t2.y}; k2[2*j+1] = (f32x2){t2.z, t2.w};
        }

        // --- scalars (exact rank-2 recurrence; z = rn*inv_d*y, unscaled)
        const float rn1 = rs_cur.x, rn2 = rs_cur.y;
        const float rn1sq = rn1 * rn1;
        const float rn2sq = rn2 * rn2;
        const float i1   = __builtin_amdgcn_rcpf(1.0f + rn1sq * e11);
        const float beta = rn1sq * e21 * i1;
        const float i2   = __builtin_amdgcn_rcpf(1.0f + rn2sq * (e22 - beta * e21));
        const float p2r0 = y2r0 - beta * y1r0;
        const float p2r1 = y2r1 - beta * y1r1;
        const float za1  = rn1 * i1;
        const float za2  = rn2 * i2;
        if (o8 == 0) {
            *(float2*)(Zb + (size_t)(2*i)     * HH + r0) =
                make_float2(za1 * y1r0, za1 * y1r1);
            *(float2*)(Zb + (size_t)(2*i + 1) * HH + r0) =
                make_float2(za2 * p2r0, za2 * p2r1);
        }

        // --- rank-2 update of A
        const float cA1 = rn1sq * i1, cA2 = rn2sq * i2;
        const f32x2 u10 = {cA1 * y1r0, cA1 * y1r0};
        const f32x2 u11 = {cA1 * y1r1, cA1 * y1r1};
        const f32x2 u20 = {cA2 * p2r0, cA2 * p2r0};
        const f32x2 u21 = {cA2 * p2r1, cA2 * p2r1};
        const f32x2 bbv = {beta, beta};
        #pragma unroll
        for (int j = 0; j < 8; j++) {
            f32x2 pp = av2[j] - bbv * av1[j];
            Ar0[j] = Ar0[j] - u10 * av1[j] - u20 * pp;
            Ar1[j] = Ar1[j] - u11 * av1[j] - u21 * pp;
        }

        rs_cur = rs_nxt;
        if (i + 2 < NI) rs_nxt = ((const float2*)rn_b)[i + 2];
    }
}

// ---------------------------------------------------------------------------
// Phase 2a: G[b][i] = V_chunk^T @ (diag(s) Z_chunk)  (HxH).
// ---------------------------------------------------------------------------
__global__ __launch_bounds__(256) void gram_kernel(
    const float* __restrict__ V, const float* __restrict__ Z,
    const float* __restrict__ Sarr, float* __restrict__ G)
{
    const int bi = blockIdx.x;                 // b*NCH + chunk
    const int r0 = blockIdx.y * 64;

    const float* Vc = V + (size_t)bi * CC * HH;
    const float* Ac = Z + (size_t)bi * CC * HH;

    __shared__ float vT[32][68];
    __shared__ float aT[32][132];

    const int tid = threadIdx.x;
    const int tx = tid & 15, ty = tid >> 4;

    float acc[4][8];
    #pragma unroll
    for (int i = 0; i < 4; i++)
        #pragma unroll
        for (int j = 0; j < 8; j++) acc[i][j] = 0.f;

    for (int s0 = 0; s0 < CC; s0 += 32) {
        #pragma unroll
        for (int l = 0; l < 2; l++) {
            int f = tid + l * 256;
            int sr = f >> 4, rc = f & 15;
            float4 v = *(const float4*)(Vc + (size_t)(s0 + sr) * HH + r0 + rc * 4);
            *(float4*)&vT[sr][rc * 4] = v;
        }
        #pragma unroll
        for (int l = 0; l < 4; l++) {
            int f = tid + l * 256;
            int sr = f >> 5, cc = f & 31;
            float sv = Sarr[(size_t)bi * CC + s0 + sr];
            float4 v = *(const float4*)(Ac + (size_t)(s0 + sr) * HH + cc * 4);
            v.x *= sv; v.y *= sv; v.z *= sv; v.w *= sv;
            *(float4*)&aT[sr][cc * 4] = v;
        }
        __syncthreads();
        #pragma unroll
        for (int ss = 0; ss < 32; ss++) {
            float4 vv = *(const float4*)&vT[ss][ty * 4];
            float4 a0 = *(const float4*)&aT[ss][tx * 8];
            float4 a1 = *(const float4*)&aT[ss][tx * 8 + 4];
            float va[4] = {vv.x, vv.y, vv.z, vv.w};
            float aa[8] = {a0.x, a0.y, a0.z, a0.w, a1.x, a1.y, a1.z, a1.w};
            #pragma unroll
            for (int i = 0; i < 4; i++)
                #pragma unroll
                for (int j = 0; j < 8; j++)
                    acc[i][j] += va[i] * aa[j];
        }
        __syncthreads();
    }

    #pragma unroll
    for (int i = 0; i < 4; i++) {
        float* gp = G + ((size_t)bi * HH + r0 + ty * 4 + i) * HH + tx * 8;
        float4 o0 = {acc[i][0], acc[i][1], acc[i][2], acc[i][3]};
        float4 o1 = {acc[i][4], acc[i][5], acc[i][6], acc[i][7]};
        *(float4*)gp       = o0;
        *(float4*)(gp + 4) = o1;
    }
}

// ---------------------------------------------------------------------------
// Phase 2b: exclusive prefix over chunks: Mpre[b][i] = sum_{j<i} G[b][j].
// ---------------------------------------------------------------------------
__global__ __launch_bounds__(256) void prefix_kernel(
    const float* __restrict__ G, float* __restrict__ Mpre)
{
    const int b   = blockIdx.x;
    const int idx = blockIdx.y * 256 + threadIdx.x;
    float run = 0.f;
    for (int i = 0; i < NCH; i++) {
        size_t off = ((size_t)b * NCH + i) * HH * HH + idx;
        Mpre[off] = run;
        run += G[off];
    }
}

// ---------------------------------------------------------------------------
// Phase 2c: O_half = Q_half @ Mpre^T + tril(Q_half @ (diag(s)Z)^T) @ V_chunk.
// ---------------------------------------------------------------------------
__global__ __launch_bounds__(256) void ochunk_kernel(
    const float* __restrict__ Q, const float* __restrict__ Z,
    const float* __restrict__ Sarr, const float* __restrict__ V,
    const float* __restrict__ Mpre, float* __restrict__ O)
{
    const int bi = blockIdx.x;
    const int t0 = blockIdx.y * 64;            // local t base within chunk

    const float* Qc = Q    + (size_t)bi * CC * HH;
    const float* Ac = Z    + (size_t)bi * CC * HH;
    const float* Vc = V    + (size_t)bi * CC * HH;
    const float* Mp = Mpre + (size_t)bi * HH * HH;
    float*       Oc = O    + (size_t)bi * CC * HH;

    __shared__ float S[64][132];
    __shared__ float xT[32][68];
    __shared__ float wT[32][132];

    const int tid = threadIdx.x;
    const int tx = tid & 15, ty = tid >> 4;

    float acc[4][8];

    // ---- phase 1: S = Q_half @ (diag(s)Z)^T (K = h)
    #pragma unroll
    for (int i = 0; i < 4; i++)
        #pragma unroll
        for (int j = 0; j < 8; j++) acc[i][j] = 0.f;
    for (int k0 = 0; k0 < HH; k0 += 32) {
        #pragma unroll
        for (int l = 0; l < 2; l++) {
            int f = tid + l * 256;
            int r = f >> 3, cg = f & 7;
            float4 v = *(const float4*)(Qc + (size_t)(t0 + r) * HH + k0 + cg * 4);
            xT[cg*4+0][r] = v.x; xT[cg*4+1][r] = v.y;
            xT[cg*4+2][r] = v.z; xT[cg*4+3][r] = v.w;
        }
        #pragma unroll
        for (int l = 0; l < 4; l++) {
            int f = tid + l * 256;
            int sr = f >> 3, cg = f & 7;
            float sv = Sarr[(size_t)bi * CC + sr];
            float4 v = *(const float4*)(Ac + (size_t)sr * HH + k0 + cg * 4);
            wT[cg*4+0][sr] = v.x * sv; wT[cg*4+1][sr] = v.y * sv;
            wT[cg*4+2][sr] = v.z * sv; wT[cg*4+3][sr] = v.w * sv;
        }
        __syncthreads();
        #pragma unroll
        for (int kk = 0; kk < 32; kk++) {
            float4 xv = *(const float4*)&xT[kk][ty * 4];
            float4 w0 = *(const float4*)&wT[kk][tx * 8];
            float4 w1 = *(const float4*)&wT[kk][tx * 8 + 4];
            float xa[4] = {xv.x, xv.y, xv.z, xv.w};
            float wa[8] = {w0.x, w0.y, w0.z, w0.w, w1.x, w1.y, w1.z, w1.w};
            #pragma unroll
            for (int i = 0; i < 4; i++)
                #pragma unroll
                for (int j = 0; j < 8; j++)
                    acc[i][j] += xa[i] * wa[j];
        }
        __syncthreads();
    }
    #pragma unroll
    for (int i = 0; i < 4; i++) {
        int tl = t0 + ty * 4 + i;
        float m[8];
        #pragma unroll
        for (int j = 0; j < 8; j++)
            m[j] = (tx * 8 + j <= tl) ? acc[i][j] : 0.f;
        float4 o0 = {m[0], m[1], m[2], m[3]};
        float4 o1 = {m[4], m[5], m[6], m[7]};
        *(float4*)&S[ty*4+i][tx*8]     = o0;
        *(float4*)&S[ty*4+i][tx*8 + 4] = o1;
    }

    // ---- phase 2: acc = Q_half @ Mpre^T (K = h')
    #pragma unroll
    for (int i = 0; i < 4; i++)
        #pragma unroll
        for (int j = 0; j < 8; j++) acc[i][j] = 0.f;
    for (int k0 = 0; k0 < HH; k0 += 32) {
        #pragma unroll
        for (int l = 0; l < 2; l++) {
            int f = tid + l * 256;
            int r = f >> 3, cg = f & 7;
            float4 v = *(const float4*)(Qc + (size_t)(t0 + r) * HH + k0 + cg * 4);
            xT[cg*4+0][r] = v.x; xT[cg*4+1][r] = v.y;
            xT[cg*4+2][r] = v.z; xT[cg*4+3][r] = v.w;
        }
        #pragma unroll
        for (int l = 0; l < 4; l++) {
            int f = tid + l * 256;
            int h = f >> 3, cg = f & 7;
            float4 v = *(const float4*)(Mp + (size_t)h * HH + k0 + cg * 4);
            wT[cg*4+0][h] = v.x; wT[cg*4+1][h] = v.y;
            wT[cg*4+2][h] = v.z; wT[cg*4+3][h] = v.w;
        }
        __syncthreads();
        #pragma unroll
        for (int kk = 0; kk < 32; kk++) {
            float4 xv = *(const float4*)&xT[kk][ty * 4];
            float4 w0 = *(const float4*)&wT[kk][tx * 8];
            float4 w1 = *(const float4*)&wT[kk][tx * 8 + 4];
            float xa[4] = {xv.x, xv.y, xv.z, xv.w};
            float wa[8] = {w0.x, w0.y, w0.z, w0.w, w1.x, w1.y, w1.z, w1.w};
            #pragma unroll
            for (int i = 0; i < 4; i++)
                #pragma unroll
                for (int j = 0; j < 8; j++)
                    acc[i][j] += xa[i] * wa[j];
        }
        __syncthreads();
    }

    // ---- phase 3: acc += S @ V (K = s)
    for (int s0 = 0; s0 < CC; s0 += 32) {
        #pragma unroll
        for (int l = 0; l < 4; l++) {
            int f = tid + l * 256;
            int sr = f >> 5, cc = f & 31;
            float4 v = *(const float4*)(Vc + (size_t)(s0 + sr) * HH + cc * 4);
            *(float4*)&wT[sr][cc * 4] = v;
        }
        __syncthreads();
        #pragma unroll
        for (int ss = 0; ss < 32; ss++) {
            float4 w0 = *(const float4*)&wT[ss][tx * 8];
            float4 w1 = *(const float4*)&wT[ss][tx * 8 + 4];
            float wa[8] = {w0.x, w0.y, w0.z, w0.w, w1.x, w1.y, w1.z, w1.w};
            float sv[4];
            #pragma unroll
            for (int i = 0; i < 4; i++) sv[i] = S[ty*4+i][s0 + ss];
            #pragma unroll
            for (int i = 0; i < 4; i++)
                #pragma unroll
                for (int j = 0; j < 8; j++)
                    acc[i][j] += sv[i] * wa[j];
        }
        __syncthreads();
    }

    #pragma unroll
    for (int i = 0; i < 4; i++) {
        float* op = Oc + (size_t)(t0 + ty * 4 + i) * HH + tx * 8;
        float4 o0 = {acc[i][0], acc[i][1], acc[i][2], acc[i][3]};
        float4 o1 = {acc[i][4], acc[i][5], acc[i][6], acc[i][7]};
        *(float4*)op       = o0;
        *(float4*)(op + 4) = o1;
    }
}

// ---------------------------------------------------------------------------
// Output: out[bt][d] = sum_h O[bt][h] * Wo[d][h] + bo[d]
// ---------------------------------------------------------------------------
__global__ __launch_bounds__(256) void out_kernel(
    const float* __restrict__ O, const float* __restrict__ Wo,
    const float* __restrict__ bo, float* __restrict__ out)
{
    const int row0 = blockIdx.x * 64;
    const int d0   = blockIdx.y * 128;

    __shared__ float oT[32][68];
    __shared__ float woT[32][132];

    const int tid = threadIdx.x;
    const int tx = tid & 15;
    const int ty = tid >> 4;

    float acc[4][8];
    #pragma unroll
    for (int i = 0; i < 4; i++)
        #pragma unroll
        for (int j = 0; j < 8; j++) acc[i][j] = 0.f;

    for (int k0 = 0; k0 < HH; k0 += 32) {
        #pragma unroll
        for (int l = 0; l < 2; l++) {
            int f = tid + l * 256;
            int r = f >> 3;
            int cg = f & 7;
            float4 v = *(const float4*)(O + (size_t)(row0 + r) * HH + k0 + cg * 4);
            oT[cg*4+0][r] = v.x; oT[cg*4+1][r] = v.y;
            oT[cg*4+2][r] = v.z; oT[cg*4+3][r] = v.w;
        }
        #pragma unroll
        for (int l = 0; l < 4; l++) {
            int f = tid + l * 256;
            int d = f >> 3;
            int cg = f & 7;
            float4 v = *(const float4*)(Wo + (size_t)(d0 + d) * HH + k0 + cg * 4);
            woT[cg*4+0][d] = v.x; woT[cg*4+1][d] = v.y;
            woT[cg*4+2][d] = v.z; woT[cg*4+3][d] = v.w;
        }
        __syncthreads();
        #pragma unroll
        for (int kk = 0; kk < 32; kk++) {
            float4 ov = *(const float4*)&oT[kk][ty * 4];
            float4 w0 = *(const float4*)&woT[kk][tx * 8];
            float4 w1 = *(const float4*)&woT[kk][tx * 8 + 4];
            float oa[4] = {ov.x, ov.y, ov.z, ov.w};
            float wa[8] = {w0.x, w0.y, w0.z, w0.w, w1.x, w1.y, w1.z, w1.w};
            #pragma unroll
            for (int i = 0; i < 4; i++)
                #pragma unroll
                for (int j = 0; j < 8; j++)
                    acc[i][j] += oa[i] * wa[j];
        }
        __syncthreads();
    }

    #pragma unroll
    for (int i = 0; i < 4; i++) {
        int row = row0 + ty * 4 + i;
        #pragma unroll
        for (int j = 0; j < 8; j++) acc[i][j] += bo[d0 + tx * 8 + j];
        float4 o0 = {acc[i][0], acc[i][1], acc[i][2], acc[i][3]};
        float4 o1 = {acc[i][4], acc[i][5], acc[i][6], acc[i][7]};
        *(float4*)(out + (size_t)row * DD + d0 + tx * 8)     = o0;
        *(float4*)(out + (size_t)row * DD + d0 + tx * 8 + 4) = o1;
    }
}

extern "C" void kernel_launch(void* const* d_in, const int* in_sizes, int n_in,
                              void* d_out, int out_size, void* d_ws, size_t ws_size,
                              hipStream_t stream) {
    const float* x  = (const float*)d_in[0];
    const float* Wq = (const float*)d_in[1];
    const float* bq = (const float*)d_in[2];
    const float* Wk = (const float*)d_in[3];
    const float* bk = (const float*)d_in[4];
    const float* Wv = (const float*)d_in[5];
    const float* bv = (const float*)d_in[6];
    const float* Wo = (const float*)d_in[7];
    const float* bo = (const float*)d_in[8];
    float* out = (float*)d_out;

    float* ws = (float*)d_ws;
    float* Q = ws;
    float* K = ws + (size_t)BT * HH;
    float* V = ws + (size_t)2 * BT * HH;
    float* O = ws + (size_t)3 * BT * HH;

    // scratch in d_out (32 MB), all consumed before out_kernel writes it:
    //   rn @ 0 (32 KB) | s @ 32 KB (32 KB) | Z @ 1 MB (4 MB)
    //   G @ 8 MB (4 MB) | Mpre @ 12 MB (4 MB)
    float* db   = (float*)d_out;
    float* rn   = db;
    float* Sarr = db + BT;
    float* Z    = db + (1u << 18);
    float* G    = db + (1u << 21);
    float* Mpre = db + 3u * (1u << 20);

    // 1. K projection (+rn epilogue) — the only scan dependency
    projk_kernel<<<BT / 64, 512, 0, stream>>>(x, Wk, bk, K, rn);

    // 2. fused: 4 scan blocks + 252 worker blocks (Q proj + s, V proj)
    fused_kernel<<<BB + 252, 512, 0, stream>>>(
        x, Wq, bq, Wv, bv, K, rn, Q, V, Sarr, Z);

    // 3. chunked phase-2 (alpha = s*z folded into staging)
    dim3 ggrid(BB * NCH, 2);
    gram_kernel<<<ggrid, 256, 0, stream>>>(V, Z, Sarr, G);

    dim3 fgrid(BB, HH * HH / 256);
    prefix_kernel<<<fgrid, 256, 0, stream>>>(G, Mpre);

    dim3 cgrid(BB * NCH, 2);
    ochunk_kernel<<<cgrid, 256, 0, stream>>>(Q, Z, Sarr, V, Mpre, O);

    dim3 ogrid(BT / 64, DD / 128);
    out_kernel<<<ogrid, 256, 0, stream>>>(O, Wo, bo, out);
}